// Round 1
// baseline (489.473 us; speedup 1.0000x reference)
//
#include <hip/hip_runtime.h>
#include <math.h>

#define C_IN  128
#define C_HID 64
#define C_OUT 40

// ---------------- degree / norm ----------------
__global__ void k_deg_init(float* __restrict__ deg, int n) {
    int i = blockIdx.x * 256 + threadIdx.x;
    if (i < n) deg[i] = 1.0f;   // self loop
}

__global__ void k_deg_count(const int* __restrict__ dst, float* __restrict__ deg, int e) {
    int i = blockIdx.x * 256 + threadIdx.x;
    if (i < e) atomicAdd(&deg[dst[i]], 1.0f);
}

__global__ void k_dinv(float* __restrict__ deg, int n) {
    int i = blockIdx.x * 256 + threadIdx.x;
    if (i < n) deg[i] = rsqrtf(deg[i]);   // in place: deg -> dinv
}

// ---------------- GEMM1: h1 = X @ W1   (N x 128)(128 x 64) ----------------
// 256 threads: 4 rows x 64 cols per block; W1 fully staged in LDS (32 KB)
__global__ void k_gemm1(const float* __restrict__ X, const float* __restrict__ W1,
                        float* __restrict__ h1, int n) {
    __shared__ float w[C_IN * C_HID];
    for (int t = threadIdx.x; t < C_IN * C_HID; t += 256) w[t] = W1[t];
    __syncthreads();
    int r = threadIdx.x >> 6;        // wave-uniform row within block
    int c = threadIdx.x & 63;
    int row = blockIdx.x * 4 + r;
    if (row >= n) return;
    const float* xr = X + (size_t)row * C_IN;
    float acc = 0.f;
#pragma unroll 8
    for (int k = 0; k < C_IN; ++k)
        acc = fmaf(xr[k], w[k * C_HID + c], acc);
    h1[(size_t)row * C_HID + c] = acc;
}

// ---------------- layer-1 aggregation ----------------
__global__ void k_agg1_self(const float* __restrict__ h1, const float* __restrict__ dinv,
                            float* __restrict__ out1, int total) {
    int i = blockIdx.x * 256 + threadIdx.x;
    if (i < total) {
        int node = i >> 6;
        float di = dinv[node];
        out1[i] = di * di * h1[i];
    }
}

// one wave per edge: lanes = 64 channels (coalesced gather + coalesced atomic scatter)
__global__ void k_agg1_edge(const int* __restrict__ src, const int* __restrict__ dst,
                            const float* __restrict__ dinv, const float* __restrict__ h1,
                            float* __restrict__ out1, int e) {
    int tid = blockIdx.x * 256 + threadIdx.x;
    int eid = tid >> 6;
    int c   = tid & 63;
    if (eid >= e) return;
    int s = src[eid], d = dst[eid];
    float norm = dinv[s] * dinv[d];
    atomicAdd(&out1[(size_t)d * C_HID + c], norm * h1[(size_t)s * C_HID + c]);
}

__global__ void k_relu_bias(float* __restrict__ x, const float* __restrict__ b, int total) {
    int i = blockIdx.x * 256 + threadIdx.x;
    if (i < total) {
        float v = x[i] + b[i & 63];
        x[i] = v > 0.f ? v : 0.f;
    }
}

// ---------------- GEMM2: h2 = x1 @ W2   (N x 64)(64 x 40) ----------------
__global__ void k_gemm2(const float* __restrict__ X, const float* __restrict__ W2,
                        float* __restrict__ h2, int total /* n*C_OUT */) {
    __shared__ float w[C_HID * C_OUT];
    for (int t = threadIdx.x; t < C_HID * C_OUT; t += 256) w[t] = W2[t];
    __syncthreads();
    int idx = blockIdx.x * 256 + threadIdx.x;
    if (idx >= total) return;
    int row = idx / C_OUT;
    int c   = idx - row * C_OUT;
    const float* xr = X + (size_t)row * C_HID;
    float acc = 0.f;
#pragma unroll 8
    for (int k = 0; k < C_HID; ++k)
        acc = fmaf(xr[k], w[k * C_OUT + c], acc);
    h2[idx] = acc;
}

// ---------------- layer-2 aggregation (into d_out) ----------------
__global__ void k_agg2_self(const float* __restrict__ h2, const float* __restrict__ dinv,
                            float* __restrict__ out, int total) {
    int i = blockIdx.x * 256 + threadIdx.x;
    if (i < total) {
        int node = i / C_OUT;
        float di = dinv[node];
        out[i] = di * di * h2[i];
    }
}

__global__ void k_agg2_edge(const int* __restrict__ src, const int* __restrict__ dst,
                            const float* __restrict__ dinv, const float* __restrict__ h2,
                            float* __restrict__ out, int e) {
    int tid = blockIdx.x * 256 + threadIdx.x;
    int eid = tid / C_OUT;
    int c   = tid - eid * C_OUT;
    if (eid >= e) return;
    int s = src[eid], d = dst[eid];
    float norm = dinv[s] * dinv[d];
    atomicAdd(&out[(size_t)d * C_OUT + c], norm * h2[(size_t)s * C_OUT + c]);
}

// ---------------- bias + log_softmax, one wave per node ----------------
__global__ void k_bias_logsoftmax(float* __restrict__ out, const float* __restrict__ b2, int n) {
    int wave = (blockIdx.x * 256 + threadIdx.x) >> 6;
    int lane = threadIdx.x & 63;
    if (wave >= n) return;
    float* row = out + (size_t)wave * C_OUT;
    float v = -INFINITY;
    if (lane < C_OUT) v = row[lane] + b2[lane];
    float m = v;
    for (int off = 32; off; off >>= 1) m = fmaxf(m, __shfl_xor(m, off));
    float ex = (lane < C_OUT) ? expf(v - m) : 0.f;
    float ss = ex;
    for (int off = 32; off; off >>= 1) ss += __shfl_xor(ss, off);
    float lse = m + logf(ss);
    if (lane < C_OUT) row[lane] = v - lse;
}

extern "C" void kernel_launch(void* const* d_in, const int* in_sizes, int n_in,
                              void* d_out, int out_size, void* d_ws, size_t ws_size,
                              hipStream_t stream) {
    const float* X  = (const float*)d_in[0];
    const int*   src = (const int*)d_in[1];
    const int*   dst = (const int*)d_in[2];
    const float* W1 = (const float*)d_in[3];
    const float* b1 = (const float*)d_in[4];
    const float* W2 = (const float*)d_in[5];
    const float* b2 = (const float*)d_in[6];
    float* out = (float*)d_out;

    const int N = in_sizes[0] / C_IN;
    const int E = in_sizes[1];

    // workspace layout (f32): dinv[N] | h1[N*64] | out1[N*64]   (h2 reuses h1 slot)
    char* ws = (char*)d_ws;
    float* dinv = (float*)ws;
    float* h1   = (float*)(ws + ((size_t)N * 4 + 255 & ~(size_t)255));
    float* out1 = h1 + (size_t)N * C_HID;
    float* h2   = h1;  // reuse: h1 dead after layer-1 aggregation

    // degrees -> dinv
    k_deg_init <<<(N + 255) / 256, 256, 0, stream>>>(dinv, N);
    k_deg_count<<<(E + 255) / 256, 256, 0, stream>>>(dst, dinv, E);
    k_dinv     <<<(N + 255) / 256, 256, 0, stream>>>(dinv, N);

    // layer 1
    k_gemm1    <<<(N + 3) / 4, 256, 0, stream>>>(X, W1, h1, N);
    k_agg1_self<<<((N * C_HID) + 255) / 256, 256, 0, stream>>>(h1, dinv, out1, N * C_HID);
    k_agg1_edge<<<((E * 64) + 255) / 256, 256, 0, stream>>>(src, dst, dinv, h1, out1, E);
    k_relu_bias<<<((N * C_HID) + 255) / 256, 256, 0, stream>>>(out1, b1, N * C_HID);

    // layer 2
    k_gemm2    <<<((N * C_OUT) + 255) / 256, 256, 0, stream>>>(out1, W2, h2, N * C_OUT);
    k_agg2_self<<<((N * C_OUT) + 255) / 256, 256, 0, stream>>>(h2, dinv, out, N * C_OUT);
    k_agg2_edge<<<((E * C_OUT) + 255) / 256, 256, 0, stream>>>(src, dst, dinv, h2, out, E);

    // epilogue
    k_bias_logsoftmax<<<(N + 3) / 4, 256, 0, stream>>>(out, b2, N);
}

// Round 2
// 317.102 us; speedup vs baseline: 1.5436x; 1.5436x over previous
//
#include <hip/hip_runtime.h>
#include <math.h>

#define C_IN  128
#define C_HID 64
#define C_OUT 40

// ---------------- degree count (int atomics) ----------------
__global__ void k_deg_count(const int* __restrict__ dst, int* __restrict__ deg, int e) {
    int i = blockIdx.x * 256 + threadIdx.x;
    if (i < e) atomicAdd(&deg[dst[i]], 1);
}

// ---------------- prefix scan over deg -> row_start / cursor ----------------
__global__ void k_scan_partial(const int* __restrict__ deg, int* __restrict__ bsum, int n) {
    __shared__ int lds[1024];
    int i = blockIdx.x * 1024 + threadIdx.x;
    lds[threadIdx.x] = (i < n) ? deg[i] : 0;
    __syncthreads();
    for (int s = 512; s > 0; s >>= 1) {
        if (threadIdx.x < s) lds[threadIdx.x] += lds[threadIdx.x + s];
        __syncthreads();
    }
    if (threadIdx.x == 0) bsum[blockIdx.x] = lds[0];
}

__global__ void k_scan_bsum(int* __restrict__ bsum, int nb) {
    if (threadIdx.x == 0) {
        int run = 0;
        for (int i = 0; i < nb; ++i) { int v = bsum[i]; bsum[i] = run; run += v; }
    }
}

__global__ void k_scan_final(const int* __restrict__ deg, const int* __restrict__ bsum,
                             int* __restrict__ row_start, int* __restrict__ cursor, int n) {
    __shared__ int wsum[16];
    int i = blockIdx.x * 1024 + threadIdx.x;
    int v = (i < n) ? deg[i] : 0;
    int orig = v;
    int lane = threadIdx.x & 63, wid = threadIdx.x >> 6;
    for (int off = 1; off < 64; off <<= 1) { int t = __shfl_up(v, off); if (lane >= off) v += t; }
    if (lane == 63) wsum[wid] = v;
    __syncthreads();
    if (wid == 0) {
        int w = (lane < 16) ? wsum[lane] : 0;
        for (int off = 1; off < 16; off <<= 1) { int t = __shfl_up(w, off); if (lane >= off) w += t; }
        if (lane < 16) wsum[lane] = w;
    }
    __syncthreads();
    int base = bsum[blockIdx.x] + (wid > 0 ? wsum[wid - 1] : 0);
    int excl = base + v - orig;
    if (i < n) { row_start[i] = excl; cursor[i] = excl; }
    if (i == n - 1) row_start[n] = excl + orig;  // == E
}

__global__ void k_dinv(const int* __restrict__ deg, float* __restrict__ dinv, int n) {
    int i = blockIdx.x * 256 + threadIdx.x;
    if (i < n) dinv[i] = rsqrtf((float)deg[i] + 1.0f);  // +1 self loop
}

// ---------------- CSR scatter: csr_src grouped by dst ----------------
__global__ void k_scatter(const int* __restrict__ src, const int* __restrict__ dst,
                          int* __restrict__ cursor, int* __restrict__ csr_src, int e) {
    int i = blockIdx.x * 256 + threadIdx.x;
    if (i < e) {
        int pos = atomicAdd(&cursor[dst[i]], 1);
        csr_src[pos] = src[i];
    }
}

// ---------------- GEMM1: h1s = dinv[row] * (X @ W1)  (N x 64) ----------------
__global__ void k_gemm1(const float* __restrict__ X, const float* __restrict__ W1,
                        const float* __restrict__ dinv, float* __restrict__ h1s, int n) {
    __shared__ float w[C_IN * C_HID];
    for (int t = threadIdx.x; t < C_IN * C_HID; t += 256) w[t] = W1[t];
    __syncthreads();
    int r = threadIdx.x >> 6;
    int c = threadIdx.x & 63;
    int row = blockIdx.x * 4 + r;
    if (row >= n) return;
    const float* xr = X + (size_t)row * C_IN;
    float acc = 0.f;
#pragma unroll 8
    for (int k = 0; k < C_IN; ++k)
        acc = fmaf(xr[k], w[k * C_HID + c], acc);
    h1s[(size_t)row * C_HID + c] = dinv[row] * acc;
}

// ---------------- layer-1 gather-aggregate + bias + relu ----------------
// out1[d] = relu(dinv[d] * (h1s[d] + sum_{s in N(d)} h1s[s]) + b1)
__global__ void k_agg1(const int* __restrict__ row_start, const int* __restrict__ csr_src,
                       const float* __restrict__ h1s, const float* __restrict__ dinv,
                       const float* __restrict__ b1, float* __restrict__ out1, int n) {
    int node = (blockIdx.x * 256 + threadIdx.x) >> 6;
    int lane = threadIdx.x & 63;
    if (node >= n) return;
    int beg = row_start[node], end = row_start[node + 1];
    float acc = h1s[(size_t)node * C_HID + lane];  // self term (prescaled by dinv[node])
    for (int j = beg; j < end; j += 64) {
        int sv = (j + lane < end) ? csr_src[j + lane] : 0;
        int m = min(64, end - j);
        for (int k = 0; k < m; ++k) {
            int s = __shfl(sv, k);
            acc += h1s[(size_t)s * C_HID + lane];
        }
    }
    float v = dinv[node] * acc + b1[lane];
    out1[(size_t)node * C_HID + lane] = v > 0.f ? v : 0.f;
}

// ---------------- GEMM2: h2s = dinv[row] * (out1 @ W2)  (N x 40) ----------------
__global__ void k_gemm2(const float* __restrict__ X, const float* __restrict__ W2,
                        const float* __restrict__ dinv, float* __restrict__ h2s, int total) {
    __shared__ float w[C_HID * C_OUT];
    for (int t = threadIdx.x; t < C_HID * C_OUT; t += 256) w[t] = W2[t];
    __syncthreads();
    int idx = blockIdx.x * 256 + threadIdx.x;
    if (idx >= total) return;
    int row = idx / C_OUT;
    int c   = idx - row * C_OUT;
    const float* xr = X + (size_t)row * C_HID;
    float acc = 0.f;
#pragma unroll 8
    for (int k = 0; k < C_HID; ++k)
        acc = fmaf(xr[k], w[k * C_OUT + c], acc);
    h2s[idx] = dinv[row] * acc;
}

// ---------------- layer-2 gather-aggregate + bias + log_softmax ----------------
__global__ void k_agg2(const int* __restrict__ row_start, const int* __restrict__ csr_src,
                       const float* __restrict__ h2s, const float* __restrict__ dinv,
                       const float* __restrict__ b2, float* __restrict__ out, int n) {
    int node = (blockIdx.x * 256 + threadIdx.x) >> 6;
    int lane = threadIdx.x & 63;
    if (node >= n) return;
    int beg = row_start[node], end = row_start[node + 1];
    float acc = (lane < C_OUT) ? h2s[(size_t)node * C_OUT + lane] : 0.f;
    for (int j = beg; j < end; j += 64) {
        int sv = (j + lane < end) ? csr_src[j + lane] : 0;
        int m = min(64, end - j);
        for (int k = 0; k < m; ++k) {
            int s = __shfl(sv, k);
            if (lane < C_OUT) acc += h2s[(size_t)s * C_OUT + lane];
        }
    }
    float v = (lane < C_OUT) ? dinv[node] * acc + b2[lane] : -INFINITY;
    float mx = v;
    for (int off = 32; off; off >>= 1) mx = fmaxf(mx, __shfl_xor(mx, off));
    float ex = (lane < C_OUT) ? expf(v - mx) : 0.f;
    float ss = ex;
    for (int off = 32; off; off >>= 1) ss += __shfl_xor(ss, off);
    float lse = mx + logf(ss);
    if (lane < C_OUT) out[(size_t)node * C_OUT + lane] = v - lse;
}

extern "C" void kernel_launch(void* const* d_in, const int* in_sizes, int n_in,
                              void* d_out, int out_size, void* d_ws, size_t ws_size,
                              hipStream_t stream) {
    const float* X   = (const float*)d_in[0];
    const int*   src = (const int*)d_in[1];
    const int*   dst = (const int*)d_in[2];
    const float* W1  = (const float*)d_in[3];
    const float* b1  = (const float*)d_in[4];
    const float* W2  = (const float*)d_in[5];
    const float* b2  = (const float*)d_in[6];
    float* out = (float*)d_out;

    const int N = in_sizes[0] / C_IN;
    const int E = in_sizes[1];

    // workspace layout
    char* ws = (char*)d_ws;
    size_t off = 0;
    auto take = [&](size_t bytes) { char* p = ws + off; off = (off + bytes + 255) & ~(size_t)255; return p; };
    int*   deg       = (int*)  take((size_t)N * 4);
    int*   row_start = (int*)  take((size_t)(N + 1) * 4);
    int*   cursor    = (int*)  take((size_t)N * 4);
    int*   bsum      = (int*)  take(1024 * 4);
    int*   csr_src   = (int*)  take((size_t)E * 4);
    float* dinv      = (float*)take((size_t)N * 4);
    float* h1s       = (float*)take((size_t)N * C_HID * 4);
    float* out1      = (float*)take((size_t)N * C_HID * 4);
    float* h2s       = h1s;  // h1s dead after k_agg1

    const int nb = (N + 1023) / 1024;

    hipMemsetAsync(deg, 0, (size_t)N * 4, stream);
    k_deg_count  <<<(E + 255) / 256, 256, 0, stream>>>(dst, deg, E);
    k_scan_partial<<<nb, 1024, 0, stream>>>(deg, bsum, N);
    k_scan_bsum  <<<1, 64, 0, stream>>>(bsum, nb);
    k_scan_final <<<nb, 1024, 0, stream>>>(deg, bsum, row_start, cursor, N);
    k_dinv       <<<(N + 255) / 256, 256, 0, stream>>>(deg, dinv, N);
    k_scatter    <<<(E + 255) / 256, 256, 0, stream>>>(src, dst, cursor, csr_src, E);

    k_gemm1      <<<(N + 3) / 4, 256, 0, stream>>>(X, W1, dinv, h1s, N);
    k_agg1       <<<((size_t)N * 64 + 255) / 256, 256, 0, stream>>>(row_start, csr_src, h1s, dinv, b1, out1, N);

    k_gemm2      <<<((size_t)N * C_OUT + 255) / 256, 256, 0, stream>>>(out1, W2, dinv, h2s, N * C_OUT);
    k_agg2       <<<((size_t)N * 64 + 255) / 256, 256, 0, stream>>>(row_start, csr_src, h2s, dinv, b2, out, N);
}

// Round 3
// 215.362 us; speedup vs baseline: 2.2728x; 1.4724x over previous
//
#include <hip/hip_runtime.h>
#include <math.h>

#define C_IN  128
#define C_HID 64
#define C_OUT 40

// ---------------- degree count (int atomics) ----------------
__global__ void k_deg_count(const int* __restrict__ dst, int* __restrict__ deg, int e) {
    int i = blockIdx.x * 256 + threadIdx.x;
    if (i < e) atomicAdd(&deg[dst[i]], 1);
}

// ---------------- prefix scan over deg -> row_start / cursor ----------------
__global__ void k_scan_partial(const int* __restrict__ deg, int* __restrict__ bsum, int n) {
    __shared__ int lds[1024];
    int i = blockIdx.x * 1024 + threadIdx.x;
    lds[threadIdx.x] = (i < n) ? deg[i] : 0;
    __syncthreads();
    for (int s = 512; s > 0; s >>= 1) {
        if (threadIdx.x < s) lds[threadIdx.x] += lds[threadIdx.x + s];
        __syncthreads();
    }
    if (threadIdx.x == 0) bsum[blockIdx.x] = lds[0];
}

__global__ void k_scan_bsum(int* __restrict__ bsum, int nb) {
    if (threadIdx.x == 0) {
        int run = 0;
        for (int i = 0; i < nb; ++i) { int v = bsum[i]; bsum[i] = run; run += v; }
    }
}

__global__ void k_scan_final(const int* __restrict__ deg, const int* __restrict__ bsum,
                             int* __restrict__ row_start, int* __restrict__ cursor, int n) {
    __shared__ int wsum[16];
    int i = blockIdx.x * 1024 + threadIdx.x;
    int v = (i < n) ? deg[i] : 0;
    int orig = v;
    int lane = threadIdx.x & 63, wid = threadIdx.x >> 6;
    for (int off = 1; off < 64; off <<= 1) { int t = __shfl_up(v, off); if (lane >= off) v += t; }
    if (lane == 63) wsum[wid] = v;
    __syncthreads();
    if (wid == 0) {
        int w = (lane < 16) ? wsum[lane] : 0;
        for (int off = 1; off < 16; off <<= 1) { int t = __shfl_up(w, off); if (lane >= off) w += t; }
        if (lane < 16) wsum[lane] = w;
    }
    __syncthreads();
    int base = bsum[blockIdx.x] + (wid > 0 ? wsum[wid - 1] : 0);
    int excl = base + v - orig;
    if (i < n) { row_start[i] = excl; cursor[i] = excl; }
    if (i == n - 1) row_start[n] = excl + orig;  // == E
}

__global__ void k_dinv(const int* __restrict__ deg, float* __restrict__ dinv, int n) {
    int i = blockIdx.x * 256 + threadIdx.x;
    if (i < n) dinv[i] = rsqrtf((float)deg[i] + 1.0f);  // +1 self loop
}

// ---------------- CSR scatter: csr_src grouped by dst ----------------
__global__ void k_scatter(const int* __restrict__ src, const int* __restrict__ dst,
                          int* __restrict__ cursor, int* __restrict__ csr_src, int e) {
    int i = blockIdx.x * 256 + threadIdx.x;
    if (i < e) {
        int pos = atomicAdd(&cursor[dst[i]], 1);
        csr_src[pos] = src[i];
    }
}

// ---------------- GEMM1: h1s = dinv[row] * (X @ W1)  (N x 64) ----------------
// 64x64 tile, K=128 fully staged. 256 threads; each thread a 4x4 register tile.
// Per k: 1 ds_read_b128 (X^T) + 1 ds_read_b128 (W) feed 16 FMAs -> VALU-bound.
__global__ void k_gemm1(const float* __restrict__ X, const float* __restrict__ W1,
                        const float* __restrict__ dinv, float* __restrict__ h1s, int n) {
    __shared__ float xt[C_IN][64];        // X^T tile: xt[k][r]       (32 KB)
    __shared__ float wl[C_IN * C_HID];    // W1 as-is: wl[k*64+c]     (32 KB)
    const int t = threadIdx.x;
    const int row0 = blockIdx.x * 64;

    for (int i = t; i < C_IN * C_HID; i += 256) wl[i] = W1[i];
    // stage X transposed: thread t covers row r = t>>2, quarter q = t&3
    {
        int r = t >> 2, q = t & 3;
        int grow = row0 + r;
        for (int j = 0; j < 8; ++j) {
            int k = q * 32 + j * 4;
            float4 v = make_float4(0.f, 0.f, 0.f, 0.f);
            if (grow < n) v = *(const float4*)(X + (size_t)grow * C_IN + k);
            xt[k + 0][r] = v.x; xt[k + 1][r] = v.y; xt[k + 2][r] = v.z; xt[k + 3][r] = v.w;
        }
    }
    __syncthreads();

    const int rg = t >> 4, cg = t & 15;
    const int r0 = rg * 4, c0 = cg * 4;
    float acc[4][4] = {};
#pragma unroll 4
    for (int k = 0; k < C_IN; ++k) {
        float4 a = *(const float4*)&xt[k][r0];
        float4 b = *(const float4*)&wl[k * C_HID + c0];
        acc[0][0] = fmaf(a.x, b.x, acc[0][0]); acc[0][1] = fmaf(a.x, b.y, acc[0][1]);
        acc[0][2] = fmaf(a.x, b.z, acc[0][2]); acc[0][3] = fmaf(a.x, b.w, acc[0][3]);
        acc[1][0] = fmaf(a.y, b.x, acc[1][0]); acc[1][1] = fmaf(a.y, b.y, acc[1][1]);
        acc[1][2] = fmaf(a.y, b.z, acc[1][2]); acc[1][3] = fmaf(a.y, b.w, acc[1][3]);
        acc[2][0] = fmaf(a.z, b.x, acc[2][0]); acc[2][1] = fmaf(a.z, b.y, acc[2][1]);
        acc[2][2] = fmaf(a.z, b.z, acc[2][2]); acc[2][3] = fmaf(a.z, b.w, acc[2][3]);
        acc[3][0] = fmaf(a.w, b.x, acc[3][0]); acc[3][1] = fmaf(a.w, b.y, acc[3][1]);
        acc[3][2] = fmaf(a.w, b.z, acc[3][2]); acc[3][3] = fmaf(a.w, b.w, acc[3][3]);
    }
#pragma unroll
    for (int i = 0; i < 4; ++i) {
        int row = row0 + r0 + i;
        if (row < n) {
            float di = dinv[row];
            float4 o = make_float4(di * acc[i][0], di * acc[i][1], di * acc[i][2], di * acc[i][3]);
            *(float4*)(h1s + (size_t)row * C_HID + c0) = o;
        }
    }
}

// ---------------- layer-1 gather-aggregate + bias + relu ----------------
__global__ void k_agg1(const int* __restrict__ row_start, const int* __restrict__ csr_src,
                       const float* __restrict__ h1s, const float* __restrict__ dinv,
                       const float* __restrict__ b1, float* __restrict__ out1, int n) {
    int node = (blockIdx.x * 256 + threadIdx.x) >> 6;
    int lane = threadIdx.x & 63;
    if (node >= n) return;
    int beg = row_start[node], end = row_start[node + 1];
    float a0 = h1s[(size_t)node * C_HID + lane];  // self term (prescaled by dinv[node])
    float a1 = 0.f, a2 = 0.f, a3 = 0.f;
    for (int j = beg; j < end; j += 64) {
        int sv = (j + lane < end) ? csr_src[j + lane] : 0;
        int m = min(64, end - j);
        int k = 0;
        for (; k + 4 <= m; k += 4) {
            int s0 = __shfl(sv, k),     s1 = __shfl(sv, k + 1);
            int s2 = __shfl(sv, k + 2), s3 = __shfl(sv, k + 3);
            a0 += h1s[(size_t)s0 * C_HID + lane];
            a1 += h1s[(size_t)s1 * C_HID + lane];
            a2 += h1s[(size_t)s2 * C_HID + lane];
            a3 += h1s[(size_t)s3 * C_HID + lane];
        }
        for (; k < m; ++k) {
            int s = __shfl(sv, k);
            a0 += h1s[(size_t)s * C_HID + lane];
        }
    }
    float acc = (a0 + a1) + (a2 + a3);
    float v = dinv[node] * acc + b1[lane];
    out1[(size_t)node * C_HID + lane] = v > 0.f ? v : 0.f;
}

// ---------------- GEMM2: h2s = dinv[row] * (out1 @ W2)  (N x 40) ----------------
// 96x40 tile, K=64. 240 active compute threads, each a 4x4 register tile.
__global__ void k_gemm2(const float* __restrict__ X2, const float* __restrict__ W2,
                        const float* __restrict__ dinv, float* __restrict__ h2s, int n) {
    __shared__ float xt[C_HID][96];        // X2^T tile (24 KB)
    __shared__ float wl[C_HID * C_OUT];    // W2 (10 KB)
    const int t = threadIdx.x;
    const int row0 = blockIdx.x * 96;

    for (int i = t; i < C_HID * C_OUT; i += 256) wl[i] = W2[i];
    // stage X2^T: 96 rows x 16 float4 = 1536 float4 over 256 threads (6 each)
    for (int idx = t; idx < 96 * 16; idx += 256) {
        int r = idx >> 4, f4 = idx & 15;
        int grow = row0 + r;
        float4 v = make_float4(0.f, 0.f, 0.f, 0.f);
        if (grow < n) v = *(const float4*)(X2 + (size_t)grow * C_HID + f4 * 4);
        int k = f4 * 4;
        xt[k + 0][r] = v.x; xt[k + 1][r] = v.y; xt[k + 2][r] = v.z; xt[k + 3][r] = v.w;
    }
    __syncthreads();

    if (t >= 240) return;
    const int rg = t / 10, cg = t - rg * 10;   // 24 x 10
    const int r0 = rg * 4, c0 = cg * 4;
    float acc[4][4] = {};
#pragma unroll 4
    for (int k = 0; k < C_HID; ++k) {
        float4 a = *(const float4*)&xt[k][r0];
        float4 b = *(const float4*)&wl[k * C_OUT + c0];
        acc[0][0] = fmaf(a.x, b.x, acc[0][0]); acc[0][1] = fmaf(a.x, b.y, acc[0][1]);
        acc[0][2] = fmaf(a.x, b.z, acc[0][2]); acc[0][3] = fmaf(a.x, b.w, acc[0][3]);
        acc[1][0] = fmaf(a.y, b.x, acc[1][0]); acc[1][1] = fmaf(a.y, b.y, acc[1][1]);
        acc[1][2] = fmaf(a.y, b.z, acc[1][2]); acc[1][3] = fmaf(a.y, b.w, acc[1][3]);
        acc[2][0] = fmaf(a.z, b.x, acc[2][0]); acc[2][1] = fmaf(a.z, b.y, acc[2][1]);
        acc[2][2] = fmaf(a.z, b.z, acc[2][2]); acc[2][3] = fmaf(a.z, b.w, acc[2][3]);
        acc[3][0] = fmaf(a.w, b.x, acc[3][0]); acc[3][1] = fmaf(a.w, b.y, acc[3][1]);
        acc[3][2] = fmaf(a.w, b.z, acc[3][2]); acc[3][3] = fmaf(a.w, b.w, acc[3][3]);
    }
#pragma unroll
    for (int i = 0; i < 4; ++i) {
        int row = row0 + r0 + i;
        if (row < n) {
            float di = dinv[row];
            float4 o = make_float4(di * acc[i][0], di * acc[i][1], di * acc[i][2], di * acc[i][3]);
            *(float4*)(h2s + (size_t)row * C_OUT + c0) = o;
        }
    }
}

// ---------------- layer-2 gather-aggregate + bias + log_softmax ----------------
__global__ void k_agg2(const int* __restrict__ row_start, const int* __restrict__ csr_src,
                       const float* __restrict__ h2s, const float* __restrict__ dinv,
                       const float* __restrict__ b2, float* __restrict__ out, int n) {
    int node = (blockIdx.x * 256 + threadIdx.x) >> 6;
    int lane = threadIdx.x & 63;
    if (node >= n) return;
    int beg = row_start[node], end = row_start[node + 1];
    float a0 = (lane < C_OUT) ? h2s[(size_t)node * C_OUT + lane] : 0.f;
    float a1 = 0.f, a2 = 0.f, a3 = 0.f;
    for (int j = beg; j < end; j += 64) {
        int sv = (j + lane < end) ? csr_src[j + lane] : 0;
        int m = min(64, end - j);
        int k = 0;
        for (; k + 4 <= m; k += 4) {
            int s0 = __shfl(sv, k),     s1 = __shfl(sv, k + 1);
            int s2 = __shfl(sv, k + 2), s3 = __shfl(sv, k + 3);
            if (lane < C_OUT) {
                a0 += h2s[(size_t)s0 * C_OUT + lane];
                a1 += h2s[(size_t)s1 * C_OUT + lane];
                a2 += h2s[(size_t)s2 * C_OUT + lane];
                a3 += h2s[(size_t)s3 * C_OUT + lane];
            }
        }
        for (; k < m; ++k) {
            int s = __shfl(sv, k);
            if (lane < C_OUT) a0 += h2s[(size_t)s * C_OUT + lane];
        }
    }
    float acc = (a0 + a1) + (a2 + a3);
    float v = (lane < C_OUT) ? dinv[node] * acc + b2[lane] : -INFINITY;
    float mx = v;
    for (int off = 32; off; off >>= 1) mx = fmaxf(mx, __shfl_xor(mx, off));
    float ex = (lane < C_OUT) ? expf(v - mx) : 0.f;
    float ss = ex;
    for (int off = 32; off; off >>= 1) ss += __shfl_xor(ss, off);
    float lse = mx + logf(ss);
    if (lane < C_OUT) out[(size_t)node * C_OUT + lane] = v - lse;
}

extern "C" void kernel_launch(void* const* d_in, const int* in_sizes, int n_in,
                              void* d_out, int out_size, void* d_ws, size_t ws_size,
                              hipStream_t stream) {
    const float* X   = (const float*)d_in[0];
    const int*   src = (const int*)d_in[1];
    const int*   dst = (const int*)d_in[2];
    const float* W1  = (const float*)d_in[3];
    const float* b1  = (const float*)d_in[4];
    const float* W2  = (const float*)d_in[5];
    const float* b2  = (const float*)d_in[6];
    float* out = (float*)d_out;

    const int N = in_sizes[0] / C_IN;
    const int E = in_sizes[1];

    // workspace layout
    char* ws = (char*)d_ws;
    size_t off = 0;
    auto take = [&](size_t bytes) { char* p = ws + off; off = (off + bytes + 255) & ~(size_t)255; return p; };
    int*   deg       = (int*)  take((size_t)N * 4);
    int*   row_start = (int*)  take((size_t)(N + 1) * 4);
    int*   cursor    = (int*)  take((size_t)N * 4);
    int*   bsum      = (int*)  take(1024 * 4);
    int*   csr_src   = (int*)  take((size_t)E * 4);
    float* dinv      = (float*)take((size_t)N * 4);
    float* h1s       = (float*)take((size_t)N * C_HID * 4);
    float* out1      = (float*)take((size_t)N * C_HID * 4);
    float* h2s       = h1s;  // h1s dead after k_agg1

    const int nb = (N + 1023) / 1024;

    hipMemsetAsync(deg, 0, (size_t)N * 4, stream);
    k_deg_count  <<<(E + 255) / 256, 256, 0, stream>>>(dst, deg, E);
    k_scan_partial<<<nb, 1024, 0, stream>>>(deg, bsum, N);
    k_scan_bsum  <<<1, 64, 0, stream>>>(bsum, nb);
    k_scan_final <<<nb, 1024, 0, stream>>>(deg, bsum, row_start, cursor, N);
    k_dinv       <<<(N + 255) / 256, 256, 0, stream>>>(deg, dinv, N);
    k_scatter    <<<(E + 255) / 256, 256, 0, stream>>>(src, dst, cursor, csr_src, E);

    k_gemm1      <<<(N + 63) / 64, 256, 0, stream>>>(X, W1, dinv, h1s, N);
    k_agg1       <<<((size_t)N * 64 + 255) / 256, 256, 0, stream>>>(row_start, csr_src, h1s, dinv, b1, out1, N);

    k_gemm2      <<<(N + 95) / 96, 256, 0, stream>>>(out1, W2, dinv, h2s, N);
    k_agg2       <<<((size_t)N * 64 + 255) / 256, 256, 0, stream>>>(row_start, csr_src, h2s, dinv, b2, out, N);
}